// Round 3
// baseline (25.626 us; speedup 1.0000x reference)
//
#include <hip/hip_runtime.h>
#include <hip/hip_bf16.h>
#include <math.h>

// Problem constants (fixed by setup_inputs): B=128, E=512, L=128, D=128, K=5
#define B_ 128
#define E_ 512
#define L_ 128
#define D_ 128
#define K_ 5
#define N_ (B_ * E_)                 // 65536 rows
#define ROWOUT (B_ * K_)             // 640 output rows
#define OUT_TENSOR_SZ (ROWOUT * L_)  // 81920

// ---------------- Kernel 1: per-row cosine similarity ----------------
// 32 lanes per row (float4 each), 2 rows per wave, 4 row-sweeps per thread.
// 2048 blocks x 256 thr = 8192 waves -> 16384 rows/sweep, 4 sweeps = 65536 rows.
#define CBLK 2048
__global__ __launch_bounds__(256) void cos_kernel(const float* __restrict__ a,
                                                  const float* __restrict__ b,
                                                  float* __restrict__ cosout) {
    const int wave_g = (blockIdx.x * 256 + threadIdx.x) >> 6;   // 0..8191
    const int lane   = threadIdx.x & 63;
    const int half   = lane >> 5;
    const int l32    = lane & 31;
    const int row0   = wave_g * 2 + half;

    float4 av[4], bv[4];
    #pragma unroll
    for (int it = 0; it < 4; ++it) {
        const size_t row = (size_t)(row0 + it * 16384);
        av[it] = reinterpret_cast<const float4*>(a)[row * (D_ / 4) + l32];
        bv[it] = reinterpret_cast<const float4*>(b)[row * (D_ / 4) + l32];
    }
    #pragma unroll
    for (int it = 0; it < 4; ++it) {
        float4 A = av[it], Bv = bv[it];
        float dot = A.x * Bv.x + A.y * Bv.y + A.z * Bv.z + A.w * Bv.w;
        float na  = A.x * A.x + A.y * A.y + A.z * A.z + A.w * A.w;
        float nb  = Bv.x * Bv.x + Bv.y * Bv.y + Bv.z * Bv.z + Bv.w * Bv.w;
        #pragma unroll
        for (int o = 16; o; o >>= 1) {       // stays within each 32-lane half
            dot += __shfl_xor(dot, o);
            na  += __shfl_xor(na,  o);
            nb  += __shfl_xor(nb,  o);
        }
        if (l32 == 0) {
            const float eps = 1e-8f;
            float denom = fmaxf(sqrtf(na), eps) * fmaxf(sqrtf(nb), eps);
            cosout[row0 + it * 16384] = dot / denom;
        }
    }
}

// ------- Kernel 2 (fused): softmax over E + top-5 + gather of selected rows ----
__global__ __launch_bounds__(512) void softmax_topk_gather_kernel(
        const float* __restrict__ cosv,
        const int* __restrict__ ids_c, const int* __restrict__ ids_e,
        const int* __restrict__ m_c,   const int* __restrict__ m_e,
        const int* __restrict__ t_c,   const int* __restrict__ t_e,
        float* __restrict__ out) {
    const int b    = blockIdx.x;
    const int e    = threadIdx.x;          // 0..511
    const int wid  = e >> 6;
    const int lane = e & 63;

    __shared__ float red[8];
    __shared__ float ps[E_];
    __shared__ int   topidx[K_];

    float v = cosv[b * E_ + e];

    // block max
    float m = v;
    #pragma unroll
    for (int o = 32; o; o >>= 1) m = fmaxf(m, __shfl_xor(m, o));
    if (lane == 0) red[wid] = m;
    __syncthreads();
    float mall = red[0];
    #pragma unroll
    for (int i = 1; i < 8; i++) mall = fmaxf(mall, red[i]);
    __syncthreads();

    // block sum of exp
    float ex = expf(v - mall);
    float s = ex;
    #pragma unroll
    for (int o = 32; o; o >>= 1) s += __shfl_xor(s, o);
    if (lane == 0) red[wid] = s;
    __syncthreads();
    float sall = 0.f;
    #pragma unroll
    for (int i = 0; i < 8; i++) sall += red[i];

    ps[e] = ex / sall;
    __syncthreads();

    // ---- top-5 entirely within wave 0, registers only, no barriers ----
    if (wid == 0) {
        float vals[8];
        #pragma unroll
        for (int j = 0; j < 8; j++) vals[j] = ps[j * 64 + lane];

        for (int k = 0; k < K_; k++) {
            float val = vals[0];
            int   idx = lane;
            #pragma unroll
            for (int j = 1; j < 8; j++) {
                if (vals[j] > val) { val = vals[j]; idx = j * 64 + lane; }
            }
            // wave argmax: larger value wins; equal value -> smaller index
            #pragma unroll
            for (int o = 32; o; o >>= 1) {
                float ov = __shfl_xor(val, o);
                int   oi = __shfl_xor(idx, o);
                if (ov > val || (ov == val && oi < idx)) { val = ov; idx = oi; }
            }
            if (lane == 0) {
                out[b * K_ + k] = val;
                topidx[k] = idx;
            }
            // invalidate winner (compile-time reg index to avoid scratch)
            #pragma unroll
            for (int j = 0; j < 8; j++) {
                if ((idx >> 6) == j && (idx & 63) == lane) vals[j] = -INFINITY;
            }
        }
    }
    __syncthreads();

    // ---- gather: wave k copies output row r = b*K + k (k = 0..4) ----
    if (wid < K_) {
        const int k = wid;
        const int r = b * K_ + k;
        const size_t crow = (size_t)(b * E_ + k) * L_;
        const size_t erow = (size_t)(b * E_ + topidx[k]) * L_;
        const int q  = lane & 31;       // int4 index within a row (0..31)
        const int hi = lane >> 5;       // 0 -> claim-side tensor, 1 -> evidence-side
        const int4* s0 = reinterpret_cast<const int4*>(hi ? (ids_e + erow) : (ids_c + crow));
        const int4* s1 = reinterpret_cast<const int4*>(hi ? (m_e   + erow) : (m_c   + crow));
        const int4* s2 = reinterpret_cast<const int4*>(hi ? (t_e   + erow) : (t_c   + crow));
        float4* d0 = reinterpret_cast<float4*>(out + 640 + (size_t)(0 + hi) * OUT_TENSOR_SZ + (size_t)r * L_);
        float4* d1 = reinterpret_cast<float4*>(out + 640 + (size_t)(2 + hi) * OUT_TENSOR_SZ + (size_t)r * L_);
        float4* d2 = reinterpret_cast<float4*>(out + 640 + (size_t)(4 + hi) * OUT_TENSOR_SZ + (size_t)r * L_);
        int4 v0 = s0[q];
        int4 v1 = s1[q];
        int4 v2 = s2[q];
        d0[q] = make_float4((float)v0.x, (float)v0.y, (float)v0.z, (float)v0.w);
        d1[q] = make_float4((float)v1.x, (float)v1.y, (float)v1.z, (float)v1.w);
        d2[q] = make_float4((float)v2.x, (float)v2.y, (float)v2.z, (float)v2.w);
    }
}

extern "C" void kernel_launch(void* const* d_in, const int* in_sizes, int n_in,
                              void* d_out, int out_size, void* d_ws, size_t ws_size,
                              hipStream_t stream) {
    const float* claim_vec    = (const float*)d_in[0];
    const float* evidence_vec = (const float*)d_in[1];
    const int*   ids_claim    = (const int*)d_in[2];
    const int*   ids_evidence = (const int*)d_in[3];
    const int*   masks_claim  = (const int*)d_in[4];
    const int*   masks_evid   = (const int*)d_in[5];
    const int*   token_claim  = (const int*)d_in[6];
    const int*   token_evid   = (const int*)d_in[7];

    float* cos_ws = (float*)d_ws;   // N_ floats
    float* out    = (float*)d_out;

    // 1) cosine per row: grid-stride x4, 8 float4 loads in flight per thread
    cos_kernel<<<CBLK, 256, 0, stream>>>(claim_vec, evidence_vec, cos_ws);
    // 2) fused softmax + top-5 + gather
    softmax_topk_gather_kernel<<<B_, 512, 0, stream>>>(cos_ws,
                                                       ids_claim, ids_evidence,
                                                       masks_claim, masks_evid,
                                                       token_claim, token_evid,
                                                       out);
}

// Round 5
// 23.493 us; speedup vs baseline: 1.0908x; 1.0908x over previous
//
#include <hip/hip_runtime.h>
#include <hip/hip_bf16.h>
#include <math.h>

// Problem constants (fixed by setup_inputs): B=128, E=512, L=128, D=128, K=5
#define B_ 128
#define E_ 512
#define L_ 128
#define D_ 128
#define K_ 5
#define N_ (B_ * E_)                 // 65536 rows
#define ROWOUT (B_ * K_)             // 640 output rows
#define OUT_TENSOR_SZ (ROWOUT * L_)  // 81920

// ---------------- Kernel 1: per-row cosine similarity ----------------
// EXACT per-row math of the R1/R2 passing versions: each of 32 lanes holds one
// float4 chunk, sequential dot within the chunk, xor-tree (16,8,4,2,1) across
// the 32-lane half. Numerics must not change (top-k tie-break vs numpy).
// ILP x2: each wave covers 4 CONSECUTIVE rows (2 iters x 2 rows), all loads
// issued before any reduction. 16384 waves = 4096 blocks x 256 threads.
__global__ __launch_bounds__(256) void cos_kernel(const float* __restrict__ a,
                                                  const float* __restrict__ b,
                                                  float* __restrict__ cosout) {
    const int wave_g = (blockIdx.x * 256 + threadIdx.x) >> 6;   // 0..16383
    const int lane   = threadIdx.x & 63;
    const int half   = lane >> 5;
    const int l32    = lane & 31;
    const int base   = wave_g * 4;

    float4 av[2], bv[2];
    #pragma unroll
    for (int it = 0; it < 2; ++it) {
        const size_t row = (size_t)(base + it * 2 + half);
        av[it] = reinterpret_cast<const float4*>(a)[row * (D_ / 4) + l32];
        bv[it] = reinterpret_cast<const float4*>(b)[row * (D_ / 4) + l32];
    }
    #pragma unroll
    for (int it = 0; it < 2; ++it) {
        float4 A = av[it], Bv = bv[it];
        float dot = A.x * Bv.x + A.y * Bv.y + A.z * Bv.z + A.w * Bv.w;
        float na  = A.x * A.x + A.y * A.y + A.z * A.z + A.w * A.w;
        float nb  = Bv.x * Bv.x + Bv.y * Bv.y + Bv.z * Bv.z + Bv.w * Bv.w;
        #pragma unroll
        for (int o = 16; o; o >>= 1) {       // stays within each 32-lane half
            dot += __shfl_xor(dot, o);
            na  += __shfl_xor(na,  o);
            nb  += __shfl_xor(nb,  o);
        }
        if (l32 == 0) {
            const float eps = 1e-8f;
            float denom = fmaxf(sqrtf(na), eps) * fmaxf(sqrtf(nb), eps);
            cosout[base + it * 2 + half] = dot / denom;
        }
    }
}

// ------- Kernel 2 (fused): softmax over E + top-5 + gather of selected rows ----
__global__ __launch_bounds__(512) void softmax_topk_gather_kernel(
        const float* __restrict__ cosv,
        const int* __restrict__ ids_c, const int* __restrict__ ids_e,
        const int* __restrict__ m_c,   const int* __restrict__ m_e,
        const int* __restrict__ t_c,   const int* __restrict__ t_e,
        float* __restrict__ out) {
    const int b    = blockIdx.x;
    const int e    = threadIdx.x;          // 0..511
    const int wid  = e >> 6;
    const int lane = e & 63;

    __shared__ float red[8];
    __shared__ float ps[E_];
    __shared__ int   topidx[K_];

    float v = cosv[b * E_ + e];

    // block max
    float m = v;
    #pragma unroll
    for (int o = 32; o; o >>= 1) m = fmaxf(m, __shfl_xor(m, o));
    if (lane == 0) red[wid] = m;
    __syncthreads();
    float mall = red[0];
    #pragma unroll
    for (int i = 1; i < 8; i++) mall = fmaxf(mall, red[i]);
    __syncthreads();

    // block sum of exp
    float ex = expf(v - mall);
    float s = ex;
    #pragma unroll
    for (int o = 32; o; o >>= 1) s += __shfl_xor(s, o);
    if (lane == 0) red[wid] = s;
    __syncthreads();
    float sall = 0.f;
    #pragma unroll
    for (int i = 0; i < 8; i++) sall += red[i];

    ps[e] = ex / sall;
    __syncthreads();

    // ---- top-5 entirely within wave 0, registers only, no barriers ----
    if (wid == 0) {
        float vals[8];
        #pragma unroll
        for (int j = 0; j < 8; j++) vals[j] = ps[j * 64 + lane];

        for (int k = 0; k < K_; k++) {
            float val = vals[0];
            int   idx = lane;
            #pragma unroll
            for (int j = 1; j < 8; j++) {
                if (vals[j] > val) { val = vals[j]; idx = j * 64 + lane; }
            }
            // wave argmax: larger value wins; equal value -> smaller index
            #pragma unroll
            for (int o = 32; o; o >>= 1) {
                float ov = __shfl_xor(val, o);
                int   oi = __shfl_xor(idx, o);
                if (ov > val || (ov == val && oi < idx)) { val = ov; idx = oi; }
            }
            if (lane == 0) {
                out[b * K_ + k] = val;
                topidx[k] = idx;
            }
            // invalidate winner (compile-time reg index to avoid scratch)
            #pragma unroll
            for (int j = 0; j < 8; j++) {
                if ((idx >> 6) == j && (idx & 63) == lane) vals[j] = -INFINITY;
            }
        }
    }
    __syncthreads();

    // ---- gather: wave k copies output row r = b*K + k (k = 0..4) ----
    if (wid < K_) {
        const int k = wid;
        const int r = b * K_ + k;
        const size_t crow = (size_t)(b * E_ + k) * L_;
        const size_t erow = (size_t)(b * E_ + topidx[k]) * L_;
        const int q  = lane & 31;       // int4 index within a row (0..31)
        const int hi = lane >> 5;       // 0 -> claim-side tensor, 1 -> evidence-side
        const int4* s0 = reinterpret_cast<const int4*>(hi ? (ids_e + erow) : (ids_c + crow));
        const int4* s1 = reinterpret_cast<const int4*>(hi ? (m_e   + erow) : (m_c   + crow));
        const int4* s2 = reinterpret_cast<const int4*>(hi ? (t_e   + erow) : (t_c   + crow));
        float4* d0 = reinterpret_cast<float4*>(out + 640 + (size_t)(0 + hi) * OUT_TENSOR_SZ + (size_t)r * L_);
        float4* d1 = reinterpret_cast<float4*>(out + 640 + (size_t)(2 + hi) * OUT_TENSOR_SZ + (size_t)r * L_);
        float4* d2 = reinterpret_cast<float4*>(out + 640 + (size_t)(4 + hi) * OUT_TENSOR_SZ + (size_t)r * L_);
        int4 v0 = s0[q];
        int4 v1 = s1[q];
        int4 v2 = s2[q];
        d0[q] = make_float4((float)v0.x, (float)v0.y, (float)v0.z, (float)v0.w);
        d1[q] = make_float4((float)v1.x, (float)v1.y, (float)v1.z, (float)v1.w);
        d2[q] = make_float4((float)v2.x, (float)v2.y, (float)v2.z, (float)v2.w);
    }
}

extern "C" void kernel_launch(void* const* d_in, const int* in_sizes, int n_in,
                              void* d_out, int out_size, void* d_ws, size_t ws_size,
                              hipStream_t stream) {
    const float* claim_vec    = (const float*)d_in[0];
    const float* evidence_vec = (const float*)d_in[1];
    const int*   ids_claim    = (const int*)d_in[2];
    const int*   ids_evidence = (const int*)d_in[3];
    const int*   masks_claim  = (const int*)d_in[4];
    const int*   masks_evid   = (const int*)d_in[5];
    const int*   token_claim  = (const int*)d_in[6];
    const int*   token_evid   = (const int*)d_in[7];

    float* cos_ws = (float*)d_ws;   // N_ floats
    float* out    = (float*)d_out;

    // 1) cosine: 4 consecutive rows per wave, loads issued before reductions
    cos_kernel<<<N_ / 16, 256, 0, stream>>>(claim_vec, evidence_vec, cos_ws);
    // 2) fused softmax + top-5 + gather
    softmax_topk_gather_kernel<<<B_, 512, 0, stream>>>(cos_ws,
                                                       ids_claim, ids_evidence,
                                                       masks_claim, masks_evid,
                                                       token_claim, token_evid,
                                                       out);
}